// Round 9
// baseline (2169.776 us; speedup 1.0000x reference)
//
#include <hip/hip_runtime.h>
#include <stdint.h>
#include <stddef.h>

#define T_STEPS 128
#define F_IN 9
#define HID 128
#define OUT_N 12
#define XROW (T_STEPS * F_IN)  // 1152

typedef __attribute__((ext_vector_type(8))) short bf16x8;
typedef __attribute__((ext_vector_type(4))) float f32x4;

#define MFMA16(a, b, c) __builtin_amdgcn_mfma_f32_16x16x32_bf16((a), (b), (c), 0, 0, 0)

__device__ __forceinline__ short f2bf(float f) {
  union { float f; uint32_t u; } v; v.f = f;
  return (short)((v.u + 0x7fffu + ((v.u >> 16) & 1u)) >> 16);  // RNE
}
// Fast nonlinearities (round-6 win): raw v_exp_f32 / v_rcp_f32; biases pre-scaled into the
// exp2 argument so each gate is fma -> exp2 -> add -> rcp.
__device__ __forceinline__ float frcp(float x) { return __builtin_amdgcn_rcpf(x); }
__device__ __forceinline__ float fexp2(float x) { return __builtin_amdgcn_exp2f(x); }
__device__ __forceinline__ float tanh_f(float x) {  // plain-arg tanh (for tanh(c))
  return 1.0f - 2.0f * frcp(1.0f + fexp2(2.8853900817779268f * x));
}

// ---------------- prep 1: W0x = Wih0 @ W_in  [512,9] -> B-frags; combined biases ----------------
// w0xf layout: [w][g][lane][8]  (per-wave 4 KB contiguous)
__global__ void prep_w0x(const float* __restrict__ W_in, const float* __restrict__ b_in,
                         const float* __restrict__ Wih0, const float* __restrict__ bih0,
                         const float* __restrict__ bhh0, const float* __restrict__ bih1,
                         const float* __restrict__ bhh1,
                         short* __restrict__ w0xf, float* __restrict__ b0x, float* __restrict__ b1) {
  int tid = threadIdx.x;             // 0..511
  int nt = tid >> 4, hl = tid & 15;  // global ntile, col-in-tile
  int w = nt >> 2, g = nt & 3;       // wave slice, gate
  int n = g * 128 + w * 16 + hl;     // original row of Wih0 (PyTorch i,f,g,o order)
  float wacc[F_IN];
#pragma unroll
  for (int f = 0; f < F_IN; ++f) wacc[f] = 0.f;
  float bacc = 0.f;
  for (int h = 0; h < HID; ++h) {
    float wv = Wih0[n * HID + h];
    bacc += wv * b_in[h];
#pragma unroll
    for (int f = 0; f < F_IN; ++f) wacc[f] += wv * W_in[h * F_IN + f];
  }
  b0x[n] = bacc + bih0[n] + bhh0[n];
  b1[n] = bih1[n] + bhh1[n];
#pragma unroll
  for (int k = 0; k < 32; ++k) {  // one K=32 tile, f<9 real, rest zero
    int quad = k >> 3, j = k & 7;
    w0xf[((w * 4 + g) * 64 + quad * 16 + hl) * 8 + j] = (k < F_IN) ? f2bf(wacc[k]) : (short)0;
  }
}

// ---------------- prep 2: per-wave-contiguous frag layouts ----------------
// whh0f: [w][kt(4)][g(4)][lane][8]   (per-wave 16 KB contiguous)
// w1f:   [w][kt(8)][g(4)][lane][8]   (per-wave 32 KB contiguous; kt<4 = Wih1, kt>=4 = Whh1)
__global__ void prep_wrec(const float* __restrict__ Whh0, const float* __restrict__ Wih1,
                          const float* __restrict__ Whh1,
                          short* __restrict__ whh0f, short* __restrict__ w1f) {
  int gt = blockIdx.x * blockDim.x + threadIdx.x;  // 0..6143
  if (gt < 2048) {
    int kt = gt >> 9, rr = gt & 511;
    int nt = rr >> 4, hl = rr & 15;
    int w = nt >> 2, g = nt & 3;
    int n = g * 128 + w * 16 + hl;
#pragma unroll
    for (int k = 0; k < 32; ++k) {
      int quad = k >> 3, j = k & 7;
      whh0f[((w * 16 + kt * 4 + g) * 64 + quad * 16 + hl) * 8 + j] =
          f2bf(Whh0[n * HID + kt * 32 + k]);
    }
  } else {
    int g2 = gt - 2048;
    int kt = g2 >> 9, rr = g2 & 511;  // kt 0..7: k<128 -> Wih1, else Whh1
    int nt = rr >> 4, hl = rr & 15;
    int w = nt >> 2, g = nt & 3;
    int n = g * 128 + w * 16 + hl;
#pragma unroll
    for (int k = 0; k < 32; ++k) {
      int quad = k >> 3, j = k & 7;
      int kg = kt * 32 + k;
      float v = (kg < HID) ? Wih1[n * HID + kg] : Whh1[n * HID + kg - HID];
      w1f[((w * 32 + kt * 4 + g) * 64 + quad * 16 + hl) * 8 + j] = f2bf(v);
    }
  }
}

// ---------------- main: 256 blocks x 512 thr (2 waves/SIMD) ----------------
// Allocator model (8 rounds of evidence): with AGPR accumulators, arch VGPRs cap at
// total_budget/2 = 128; exceeding it spills to scratch (FETCH blows up to GBs). Design rule:
// arch liveness <= ~125 at every point.
// vs round-6 champion: (1) ONE barrier per step (hazards covered by the mid-step barrier —
// validated by round-8's correct pass), (2) zero-C MFMA acc init + biases folded into the
// cell fma, (3) weight rotation confined WITHIN each MFMA run (2 groups in flight, never
// live across a barrier or the cell math — round-8's cross-barrier prefetch is what spilled).
__global__ void __launch_bounds__(512) __attribute__((amdgpu_waves_per_eu(2)))
lstm_main(const float* __restrict__ x, const short* __restrict__ w0xf,
          const short* __restrict__ whh0f, const short* __restrict__ w1f,
          const float* __restrict__ b0x, const float* __restrict__ b1,
          const float* __restrict__ Wout, const float* __restrict__ bout,
          float* __restrict__ out) {
  // h frags, A-operand-packed bf16, double buffered via pointer swap.
  // Each buffer: [4 mt][4 kt][64 lane][8] shorts = 8192 shorts (16 KB).
  __shared__ short sh[32768];        // 64 KB: h0A h0B h1A h1B
  __shared__ float h1fp[64 * HID];   // 32 KB, fp32 h1 at final step (pre-rounding)
  __shared__ float lg[64 * OUT_N];   // 3 KB logits

  const int tid = threadIdx.x;
  const int w = tid >> 6, lane = tid & 63;
  const int quad = lane >> 4, c = lane & 15;
  const int rowbase = blockIdx.x * 64;

  {  // zero all h buffers (h_{-1} = 0)
    int* si = (int*)sh;
    for (int i = tid; i < 16384; i += 512) si[i] = 0;
  }

  short* h0_cur = sh;            // written at t (phase 0)
  short* h0_prv = sh + 8192;     // read at t (phase 0)
  short* h1_cur = sh + 16384;    // written at t (phase 1)
  short* h1_prv = sh + 24576;    // read at t (phase 1)

  // per-wave weight stream bases (t-invariant, lane offset folded in)
  const short* wp0 = w0xf + (w * 4) * 512 + lane * 8;    // 4 frags, stride 512 shorts
  const short* wph = whh0f + (w * 16) * 512 + lane * 8;  // 16 frags
  const short* wp1 = w1f + (w * 32) * 512 + lane * 8;    // 32 frags

  // pre-scaled biases: gates i,f,o -> -1.4427*b (sigm); gate g(idx 2) -> +2.8854*b (tanh)
  float sb0[4], sb1[4];
#pragma unroll
  for (int g = 0; g < 4; ++g) {
    int n = g * 128 + w * 16 + c;
    float bv0 = b0x[n], bv1 = b1[n];
    sb0[g] = (g == 2) ? 2.8853900817779268f * bv0 : -1.4426950408889634f * bv0;
    sb1[g] = (g == 2) ? 2.8853900817779268f * bv1 : -1.4426950408889634f * bv1;
  }

  // writer constants: this lane's h column is hcol = w*16 + c
  const int kt_w = w >> 1;
  const int klocal = ((w & 1) << 4) + c;
  const int quadA = klocal >> 3;
  const int jA = klocal & 7;
  const int wr_off = (kt_w * 64 + quadA * 16 + quad * 4) * 8 + jA;  // + mt*2048 + r*8

  float c0[16], c1[16];
#pragma unroll
  for (int i = 0; i < 16; ++i) { c0[i] = 0.f; c1[i] = 0.f; }

  const f32x4 z4 = {0.f, 0.f, 0.f, 0.f};

  bf16x8 wA[4], wB[4];  // rotation buffers — live only inside an MFMA run
#define LDW(dst, p)                               \
  do {                                            \
    dst[0] = *(const bf16x8*)(p);                 \
    dst[1] = *(const bf16x8*)((p) + 512);         \
    dst[2] = *(const bf16x8*)((p) + 1024);        \
    dst[3] = *(const bf16x8*)((p) + 1536);        \
  } while (0)
#define MFMA_GRP(af, wg, accm)                    \
  do {                                            \
    accm[0] = MFMA16(af, wg[0], accm[0]);         \
    accm[1] = MFMA16(af, wg[1], accm[1]);         \
    accm[2] = MFMA16(af, wg[2], accm[2]);         \
    accm[3] = MFMA16(af, wg[3], accm[3]);         \
  } while (0)

  __syncthreads();

#pragma clang loop unroll(disable)
  for (int t = 0; t < T_STEPS; ++t) {
    // ====== phase 0: acc = x_t@W0x^T + h0_{t-1}@Whh0^T (zero-C init, bias folded in cell) ======
    // x A-frags (global loads issued first so they are in flight during the weight preload)
    bf16x8 xf[4];
#pragma unroll
    for (int mt = 0; mt < 4; ++mt) {
      bf16x8 v;
#pragma unroll
      for (int j = 0; j < 8; ++j) v[j] = 0;
      if (quad == 0) {
        const float* xp = x + (size_t)(rowbase + mt * 16 + c) * XROW + t * F_IN;
#pragma unroll
        for (int j = 0; j < 8; ++j) v[j] = f2bf(xp[j]);
      } else if (quad == 1) {
        v[0] = f2bf(x[(size_t)(rowbase + mt * 16 + c) * XROW + t * F_IN + 8]);
      }
      xf[mt] = v;
    }
    f32x4 acc[4][4];
    LDW(wA, wp0);   // G0 = w0x
    LDW(wB, wph);   // G1 = whh0 kt0 (in flight while G0 is consumed)
#pragma unroll
    for (int mt = 0; mt < 4; ++mt) {  // consume G0 with zero C
      acc[mt][0] = MFMA16(xf[mt], wA[0], z4);
      acc[mt][1] = MFMA16(xf[mt], wA[1], z4);
      acc[mt][2] = MFMA16(xf[mt], wA[2], z4);
      acc[mt][3] = MFMA16(xf[mt], wA[3], z4);
    }
    LDW(wA, wph + 2048);  // G2
#pragma unroll
    for (int mt = 0; mt < 4; ++mt) {
      bf16x8 af = *(const bf16x8*)(h0_prv + ((mt * 4 + 0) * 64 + lane) * 8);
      MFMA_GRP(af, wB, acc[mt]);
    }
    LDW(wB, wph + 4096);  // G3
#pragma unroll
    for (int mt = 0; mt < 4; ++mt) {
      bf16x8 af = *(const bf16x8*)(h0_prv + ((mt * 4 + 1) * 64 + lane) * 8);
      MFMA_GRP(af, wA, acc[mt]);
    }
    LDW(wA, wph + 6144);  // G4
#pragma unroll
    for (int mt = 0; mt < 4; ++mt) {
      bf16x8 af = *(const bf16x8*)(h0_prv + ((mt * 4 + 2) * 64 + lane) * 8);
      MFMA_GRP(af, wB, acc[mt]);
    }
#pragma unroll
    for (int mt = 0; mt < 4; ++mt) {  // consume G4 — no weight regs live into cell 0
      bf16x8 af = *(const bf16x8*)(h0_prv + ((mt * 4 + 3) * 64 + lane) * 8);
      MFMA_GRP(af, wA, acc[mt]);
    }
    // cell 0 (fp32, biases fused into exp2 args) + write h0_t frags
#pragma unroll
    for (int mt = 0; mt < 4; ++mt)
#pragma unroll
      for (int r = 0; r < 4; ++r) {
        float gi = frcp(1.0f + fexp2(fmaf(-1.4426950408889634f, acc[mt][0][r], sb0[0])));
        float gf = frcp(1.0f + fexp2(fmaf(-1.4426950408889634f, acc[mt][1][r], sb0[1])));
        float gg = 1.0f - 2.0f * frcp(1.0f + fexp2(fmaf(2.8853900817779268f, acc[mt][2][r], sb0[2])));
        float go = frcp(1.0f + fexp2(fmaf(-1.4426950408889634f, acc[mt][3][r], sb0[3])));
        float cn = gf * c0[mt * 4 + r] + gi * gg;
        c0[mt * 4 + r] = cn;
        float hn = go * tanh_f(cn);
        h0_cur[mt * 2048 + r * 8 + wr_off] = f2bf(hn);
      }
    __syncthreads();  // the ONE barrier per step
    // ====== phase 1: acc = h0_t@Wih1^T + h1_{t-1}@Whh1^T ======
    LDW(wA, wp1);         // G5 = w1 kt0 (loaded AFTER the barrier — never spans it)
    LDW(wB, wp1 + 2048);  // G6
#pragma unroll
    for (int mt = 0; mt < 4; ++mt) {  // consume G5, zero C
      bf16x8 af = *(const bf16x8*)(h0_cur + ((mt * 4 + 0) * 64 + lane) * 8);
      acc[mt][0] = MFMA16(af, wA[0], z4);
      acc[mt][1] = MFMA16(af, wA[1], z4);
      acc[mt][2] = MFMA16(af, wA[2], z4);
      acc[mt][3] = MFMA16(af, wA[3], z4);
    }
    LDW(wA, wp1 + 4096);  // G7
#pragma unroll
    for (int mt = 0; mt < 4; ++mt) {
      bf16x8 af = *(const bf16x8*)(h0_cur + ((mt * 4 + 1) * 64 + lane) * 8);
      MFMA_GRP(af, wB, acc[mt]);
    }
    LDW(wB, wp1 + 6144);  // G8
#pragma unroll
    for (int mt = 0; mt < 4; ++mt) {
      bf16x8 af = *(const bf16x8*)(h0_cur + ((mt * 4 + 2) * 64 + lane) * 8);
      MFMA_GRP(af, wA, acc[mt]);
    }
    LDW(wA, wp1 + 8192);  // G9
#pragma unroll
    for (int mt = 0; mt < 4; ++mt) {
      bf16x8 af = *(const bf16x8*)(h0_cur + ((mt * 4 + 3) * 64 + lane) * 8);
      MFMA_GRP(af, wB, acc[mt]);
    }
    LDW(wB, wp1 + 10240);  // G10
#pragma unroll
    for (int mt = 0; mt < 4; ++mt) {
      bf16x8 af = *(const bf16x8*)(h1_prv + ((mt * 4 + 0) * 64 + lane) * 8);
      MFMA_GRP(af, wA, acc[mt]);
    }
    LDW(wA, wp1 + 12288);  // G11
#pragma unroll
    for (int mt = 0; mt < 4; ++mt) {
      bf16x8 af = *(const bf16x8*)(h1_prv + ((mt * 4 + 1) * 64 + lane) * 8);
      MFMA_GRP(af, wB, acc[mt]);
    }
    LDW(wB, wp1 + 14336);  // G12
#pragma unroll
    for (int mt = 0; mt < 4; ++mt) {
      bf16x8 af = *(const bf16x8*)(h1_prv + ((mt * 4 + 2) * 64 + lane) * 8);
      MFMA_GRP(af, wA, acc[mt]);
    }
#pragma unroll
    for (int mt = 0; mt < 4; ++mt) {  // consume G12 — no weight regs live into cell 1
      bf16x8 af = *(const bf16x8*)(h1_prv + ((mt * 4 + 3) * 64 + lane) * 8);
      MFMA_GRP(af, wB, acc[mt]);
    }
    // cell 1 + write h1_t frags; fp32 h1 to LDS at final step only
#pragma unroll
    for (int mt = 0; mt < 4; ++mt)
#pragma unroll
      for (int r = 0; r < 4; ++r) {
        float gi = frcp(1.0f + fexp2(fmaf(-1.4426950408889634f, acc[mt][0][r], sb1[0])));
        float gf = frcp(1.0f + fexp2(fmaf(-1.4426950408889634f, acc[mt][1][r], sb1[1])));
        float gg = 1.0f - 2.0f * frcp(1.0f + fexp2(fmaf(2.8853900817779268f, acc[mt][2][r], sb1[2])));
        float go = frcp(1.0f + fexp2(fmaf(-1.4426950408889634f, acc[mt][3][r], sb1[3])));
        float cn = gf * c1[mt * 4 + r] + gi * gg;
        c1[mt * 4 + r] = cn;
        float hn = go * tanh_f(cn);
        if (t == T_STEPS - 1) h1fp[(mt * 16 + quad * 4 + r) * HID + w * 16 + c] = hn;
        h1_cur[mt * 2048 + r * 8 + wr_off] = f2bf(hn);
      }
    // no end-of-step barrier (hazards covered by the mid-step barrier of step t/t+1)
    short* tp = h0_cur; h0_cur = h0_prv; h0_prv = tp;
    tp = h1_cur; h1_cur = h1_prv; h1_prv = tp;
  }
  __syncthreads();  // h1fp complete before epilogue reads

  // ================= epilogue: logits = h1 @ Wout^T + bout, softmax over 12 =================
  {
    int row = tid >> 3, og = tid & 7;
    for (int oc = og; oc < OUT_N; oc += 8) {
      float s = bout[oc];
      const float* wo = Wout + oc * HID;
      const float* hr = h1fp + row * HID;
#pragma unroll 8
      for (int k = 0; k < HID; ++k) s += hr[k] * wo[k];
      lg[row * OUT_N + oc] = s;
    }
  }
  __syncthreads();
  if (tid < 64) {
    int row = tid;
    float m = lg[row * OUT_N];
#pragma unroll
    for (int oc = 1; oc < OUT_N; ++oc) m = fmaxf(m, lg[row * OUT_N + oc]);
    float e[OUT_N];
    float s = 0.f;
#pragma unroll
    for (int oc = 0; oc < OUT_N; ++oc) {
      e[oc] = __expf(lg[row * OUT_N + oc] - m);
      s += e[oc];
    }
    float inv = 1.0f / s;
    float* orow = out + (size_t)(rowbase + row) * OUT_N;
#pragma unroll
    for (int oc = 0; oc < OUT_N; ++oc) orow[oc] = e[oc] * inv;
  }
}

extern "C" void kernel_launch(void* const* d_in, const int* in_sizes, int n_in,
                              void* d_out, int out_size, void* d_ws, size_t ws_size,
                              hipStream_t stream) {
  const float* x    = (const float*)d_in[0];
  const float* W_in = (const float*)d_in[1];
  const float* b_in = (const float*)d_in[2];
  const float* Wih0 = (const float*)d_in[3];
  const float* Whh0 = (const float*)d_in[4];
  const float* bih0 = (const float*)d_in[5];
  const float* bhh0 = (const float*)d_in[6];
  const float* Wih1 = (const float*)d_in[7];
  const float* Whh1 = (const float*)d_in[8];
  const float* bih1 = (const float*)d_in[9];
  const float* bhh1 = (const float*)d_in[10];
  const float* Wout = (const float*)d_in[11];
  const float* bout = (const float*)d_in[12];
  float* out = (float*)d_out;

  // workspace layout (~420 KB): frag-packed bf16 weights + combined biases
  short* w0xf  = (short*)d_ws;            // 16384 shorts (32 KB)
  short* whh0f = w0xf + 16384;            // 65536 shorts (128 KB)
  short* w1f   = whh0f + 65536;           // 131072 shorts (256 KB)
  float* b0x   = (float*)(w1f + 131072);  // 512 f32
  float* b1    = b0x + 512;               // 512 f32

  prep_w0x<<<1, 512, 0, stream>>>(W_in, b_in, Wih0, bih0, bhh0, bih1, bhh1, w0xf, b0x, b1);
  prep_wrec<<<12, 512, 0, stream>>>(Whh0, Wih1, Whh1, whh0f, w1f);
  lstm_main<<<256, 512, 0, stream>>>(x, w0xf, whh0f, w1f, b0x, b1, Wout, bout, out);
}

// Round 10
// 1341.215 us; speedup vs baseline: 1.6178x; 1.6178x over previous
//
#include <hip/hip_runtime.h>
#include <stdint.h>
#include <stddef.h>

#define T_STEPS 128
#define F_IN 9
#define HID 128
#define OUT_N 12
#define XROW (T_STEPS * F_IN)  // 1152

typedef __attribute__((ext_vector_type(8))) short bf16x8;
typedef __attribute__((ext_vector_type(4))) float f32x4;

#define MFMA16(a, b, c) __builtin_amdgcn_mfma_f32_16x16x32_bf16((a), (b), (c), 0, 0, 0)

__device__ __forceinline__ short f2bf(float f) {
  union { float f; uint32_t u; } v; v.f = f;
  return (short)((v.u + 0x7fffu + ((v.u >> 16) & 1u)) >> 16);  // RNE
}
// Fast nonlinearities (round-6 win): raw v_exp_f32 / v_rcp_f32; biases pre-scaled into the
// exp2 argument so each gate is fma -> exp2 -> add -> rcp.
__device__ __forceinline__ float frcp(float x) { return __builtin_amdgcn_rcpf(x); }
__device__ __forceinline__ float fexp2(float x) { return __builtin_amdgcn_exp2f(x); }
__device__ __forceinline__ float tanh_f(float x) {  // plain-arg tanh (for tanh(c))
  return 1.0f - 2.0f * frcp(1.0f + fexp2(2.8853900817779268f * x));
}

// ---------------- prep 1: W0x = Wih0 @ W_in  [512,9] -> B-frags; combined biases ----------------
// w0xf layout: [w][g][lane][8]  (per-wave 4 KB contiguous)
__global__ void prep_w0x(const float* __restrict__ W_in, const float* __restrict__ b_in,
                         const float* __restrict__ Wih0, const float* __restrict__ bih0,
                         const float* __restrict__ bhh0, const float* __restrict__ bih1,
                         const float* __restrict__ bhh1,
                         short* __restrict__ w0xf, float* __restrict__ b0x, float* __restrict__ b1) {
  int tid = threadIdx.x;             // 0..511
  int nt = tid >> 4, hl = tid & 15;  // global ntile, col-in-tile
  int w = nt >> 2, g = nt & 3;       // wave slice, gate
  int n = g * 128 + w * 16 + hl;     // original row of Wih0 (PyTorch i,f,g,o order)
  float wacc[F_IN];
#pragma unroll
  for (int f = 0; f < F_IN; ++f) wacc[f] = 0.f;
  float bacc = 0.f;
  for (int h = 0; h < HID; ++h) {
    float wv = Wih0[n * HID + h];
    bacc += wv * b_in[h];
#pragma unroll
    for (int f = 0; f < F_IN; ++f) wacc[f] += wv * W_in[h * F_IN + f];
  }
  b0x[n] = bacc + bih0[n] + bhh0[n];
  b1[n] = bih1[n] + bhh1[n];
#pragma unroll
  for (int k = 0; k < 32; ++k) {  // one K=32 tile, f<9 real, rest zero
    int quad = k >> 3, j = k & 7;
    w0xf[((w * 4 + g) * 64 + quad * 16 + hl) * 8 + j] = (k < F_IN) ? f2bf(wacc[k]) : (short)0;
  }
}

// ---------------- prep 2: per-wave-contiguous frag layouts ----------------
// whh0f: [w][kt(4)][g(4)][lane][8]   (per-wave 16 KB contiguous)
// w1f:   [w][kt(8)][g(4)][lane][8]   (per-wave 32 KB contiguous; kt<4 = Wih1, kt>=4 = Whh1)
__global__ void prep_wrec(const float* __restrict__ Whh0, const float* __restrict__ Wih1,
                          const float* __restrict__ Whh1,
                          short* __restrict__ whh0f, short* __restrict__ w1f) {
  int gt = blockIdx.x * blockDim.x + threadIdx.x;  // 0..6143
  if (gt < 2048) {
    int kt = gt >> 9, rr = gt & 511;
    int nt = rr >> 4, hl = rr & 15;
    int w = nt >> 2, g = nt & 3;
    int n = g * 128 + w * 16 + hl;
#pragma unroll
    for (int k = 0; k < 32; ++k) {
      int quad = k >> 3, j = k & 7;
      whh0f[((w * 16 + kt * 4 + g) * 64 + quad * 16 + hl) * 8 + j] =
          f2bf(Whh0[n * HID + kt * 32 + k]);
    }
  } else {
    int g2 = gt - 2048;
    int kt = g2 >> 9, rr = g2 & 511;  // kt 0..7: k<128 -> Wih1, else Whh1
    int nt = rr >> 4, hl = rr & 15;
    int w = nt >> 2, g = nt & 3;
    int n = g * 128 + w * 16 + hl;
#pragma unroll
    for (int k = 0; k < 32; ++k) {
      int quad = k >> 3, j = k & 7;
      int kg = kt * 32 + k;
      float v = (kg < HID) ? Wih1[n * HID + kg] : Whh1[n * HID + kg - HID];
      w1f[((w * 32 + kt * 4 + g) * 64 + quad * 16 + hl) * 8 + j] = f2bf(v);
    }
  }
}

// ---------------- main: 256 blocks x 512 thr (2 waves/SIMD) ----------------
// DELAYED-PHASE-1 pipeline: iteration t computes phase1(t-1) then phase0(t). Both halves
// depend only on data published before this iteration's start (h0_{t-1}, h1_{t-2}) -> ONE
// barrier per iteration with ZERO extra pipeline registers (weight loads stay one-group-at-
// a-time, 16 regs — rounds 8/9 proved any 2-group rotation spills past the 128-arch cap).
// Also: zero-C MFMA acc init + biases pre-scaled & folded into the cell fma (register-neutral).
__global__ void __launch_bounds__(512) __attribute__((amdgpu_waves_per_eu(2)))
lstm_main(const float* __restrict__ x, const short* __restrict__ w0xf,
          const short* __restrict__ whh0f, const short* __restrict__ w1f,
          const float* __restrict__ b0x, const float* __restrict__ b1,
          const float* __restrict__ Wout, const float* __restrict__ bout,
          float* __restrict__ out) {
  // h frags, A-operand-packed bf16, double buffered via pointer swap.
  // Each buffer: [4 mt][4 kt][64 lane][8] shorts = 8192 shorts (16 KB).
  __shared__ short sh[32768];        // 64 KB: h0A h0B h1A h1B
  __shared__ float h1fp[64 * HID];   // 32 KB, fp32 h1 at final step (pre-rounding)
  __shared__ float lg[64 * OUT_N];   // 3 KB logits

  const int tid = threadIdx.x;
  const int w = tid >> 6, lane = tid & 63;
  const int quad = lane >> 4, c = lane & 15;
  const int rowbase = blockIdx.x * 64;

  {  // zero all h buffers (h_{-1} = h_{-2} = 0)
    int* si = (int*)sh;
    for (int i = tid; i < 16384; i += 512) si[i] = 0;
  }

  short* h0_cur = sh;            // written by phase0(t)
  short* h0_prv = sh + 8192;     // h0_{t-1}, read by both phases
  short* h1_cur = sh + 16384;    // written by phase1(t-1)
  short* h1_prv = sh + 24576;    // h1_{t-2}, read by phase1

  // per-wave weight stream bases (t-invariant, lane offset folded in)
  const short* wp0 = w0xf + (w * 4) * 512 + lane * 8;    // 4 frags, stride 512 shorts
  const short* wph = whh0f + (w * 16) * 512 + lane * 8;  // 16 frags
  const short* wp1 = w1f + (w * 32) * 512 + lane * 8;    // 32 frags

  // pre-scaled biases: gates i,f,o -> -1.4427*b (sigm); gate g(idx 2) -> +2.8854*b (tanh)
  float sb0[4], sb1[4];
#pragma unroll
  for (int g = 0; g < 4; ++g) {
    int n = g * 128 + w * 16 + c;
    float bv0 = b0x[n], bv1 = b1[n];
    sb0[g] = (g == 2) ? 2.8853900817779268f * bv0 : -1.4426950408889634f * bv0;
    sb1[g] = (g == 2) ? 2.8853900817779268f * bv1 : -1.4426950408889634f * bv1;
  }

  // writer constants: this lane's h column is hcol = w*16 + c
  const int kt_w = w >> 1;
  const int klocal = ((w & 1) << 4) + c;
  const int quadA = klocal >> 3;
  const int jA = klocal & 7;
  const int wr_off = (kt_w * 64 + quadA * 16 + quad * 4) * 8 + jA;  // + mt*2048 + r*8

  float c0[16], c1[16];
#pragma unroll
  for (int i = 0; i < 16; ++i) { c0[i] = 0.f; c1[i] = 0.f; }

  const f32x4 z4 = {0.f, 0.f, 0.f, 0.f};

  __syncthreads();

  // ================= prologue: phase0(t=0) =================
  {
    bf16x8 xf[4];
#pragma unroll
    for (int mt = 0; mt < 4; ++mt) {
      bf16x8 v;
#pragma unroll
      for (int j = 0; j < 8; ++j) v[j] = 0;
      if (quad == 0) {
        const float* xp = x + (size_t)(rowbase + mt * 16 + c) * XROW;
#pragma unroll
        for (int j = 0; j < 8; ++j) v[j] = f2bf(xp[j]);
      } else if (quad == 1) {
        v[0] = f2bf(x[(size_t)(rowbase + mt * 16 + c) * XROW + 8]);
      }
      xf[mt] = v;
    }
    f32x4 acc[4][4];
    {
      bf16x8 b0_ = *(const bf16x8*)(wp0);
      bf16x8 b1_ = *(const bf16x8*)(wp0 + 512);
      bf16x8 b2_ = *(const bf16x8*)(wp0 + 1024);
      bf16x8 b3_ = *(const bf16x8*)(wp0 + 1536);
#pragma unroll
      for (int mt = 0; mt < 4; ++mt) {
        acc[mt][0] = MFMA16(xf[mt], b0_, z4);
        acc[mt][1] = MFMA16(xf[mt], b1_, z4);
        acc[mt][2] = MFMA16(xf[mt], b2_, z4);
        acc[mt][3] = MFMA16(xf[mt], b3_, z4);
      }
    }
    // h0_{-1} = 0: whh0 contribution is zero — skip the 4 kt groups entirely.
#pragma unroll
    for (int mt = 0; mt < 4; ++mt)
#pragma unroll
      for (int r = 0; r < 4; ++r) {
        float gi = frcp(1.0f + fexp2(fmaf(-1.4426950408889634f, acc[mt][0][r], sb0[0])));
        float gf = frcp(1.0f + fexp2(fmaf(-1.4426950408889634f, acc[mt][1][r], sb0[1])));
        float gg = 1.0f - 2.0f * frcp(1.0f + fexp2(fmaf(2.8853900817779268f, acc[mt][2][r], sb0[2])));
        float go = frcp(1.0f + fexp2(fmaf(-1.4426950408889634f, acc[mt][3][r], sb0[3])));
        float cn = gi * gg;  // c0_{-1} = 0
        c0[mt * 4 + r] = cn;
        float hn = go * tanh_f(cn);
        h0_cur[mt * 2048 + r * 8 + wr_off] = f2bf(hn);
      }
  }
  __syncthreads();
  {  // swap h0 (h1 buffers both still zero — swap harmless/consistent)
    short* tp = h0_cur; h0_cur = h0_prv; h0_prv = tp;
    tp = h1_cur; h1_cur = h1_prv; h1_prv = tp;
  }

  // ================= main loop: iter t does phase1(t-1) then phase0(t), one barrier ==========
#pragma clang loop unroll(disable)
  for (int t = 1; t < T_STEPS; ++t) {
    // x_t loads issued first — in flight behind phase-1's whole MFMA run
    bf16x8 xf[4];
#pragma unroll
    for (int mt = 0; mt < 4; ++mt) {
      bf16x8 v;
#pragma unroll
      for (int j = 0; j < 8; ++j) v[j] = 0;
      if (quad == 0) {
        const float* xp = x + (size_t)(rowbase + mt * 16 + c) * XROW + t * F_IN;
#pragma unroll
        for (int j = 0; j < 8; ++j) v[j] = f2bf(xp[j]);
      } else if (quad == 1) {
        v[0] = f2bf(x[(size_t)(rowbase + mt * 16 + c) * XROW + t * F_IN + 8]);
      }
      xf[mt] = v;
    }
    // ---- phase1(t-1): acc1 = h0_{t-1}@Wih1^T + h1_{t-2}@Whh1^T ----
    {
      f32x4 acc[4][4];
      {
        const short* wb = wp1;
        bf16x8 b0_ = *(const bf16x8*)(wb);
        bf16x8 b1_ = *(const bf16x8*)(wb + 512);
        bf16x8 b2_ = *(const bf16x8*)(wb + 1024);
        bf16x8 b3_ = *(const bf16x8*)(wb + 1536);
#pragma unroll
        for (int mt = 0; mt < 4; ++mt) {
          bf16x8 af = *(const bf16x8*)(h0_prv + ((mt * 4 + 0) * 64 + lane) * 8);
          acc[mt][0] = MFMA16(af, b0_, z4);
          acc[mt][1] = MFMA16(af, b1_, z4);
          acc[mt][2] = MFMA16(af, b2_, z4);
          acc[mt][3] = MFMA16(af, b3_, z4);
        }
      }
#pragma clang loop unroll_count(3)
      for (int kt = 1; kt < 4; ++kt) {  // rest of Wih1, A = h0_{t-1}
        const short* wb = wp1 + kt * 2048;
        bf16x8 b0_ = *(const bf16x8*)(wb);
        bf16x8 b1_ = *(const bf16x8*)(wb + 512);
        bf16x8 b2_ = *(const bf16x8*)(wb + 1024);
        bf16x8 b3_ = *(const bf16x8*)(wb + 1536);
#pragma unroll
        for (int mt = 0; mt < 4; ++mt) {
          bf16x8 af = *(const bf16x8*)(h0_prv + ((mt * 4 + kt) * 64 + lane) * 8);
          acc[mt][0] = MFMA16(af, b0_, acc[mt][0]);
          acc[mt][1] = MFMA16(af, b1_, acc[mt][1]);
          acc[mt][2] = MFMA16(af, b2_, acc[mt][2]);
          acc[mt][3] = MFMA16(af, b3_, acc[mt][3]);
        }
      }
#pragma clang loop unroll_count(2)
      for (int kt = 0; kt < 4; ++kt) {  // Whh1, A = h1_{t-2}
        const short* wb = wp1 + (kt + 4) * 2048;
        bf16x8 b0_ = *(const bf16x8*)(wb);
        bf16x8 b1_ = *(const bf16x8*)(wb + 512);
        bf16x8 b2_ = *(const bf16x8*)(wb + 1024);
        bf16x8 b3_ = *(const bf16x8*)(wb + 1536);
#pragma unroll
        for (int mt = 0; mt < 4; ++mt) {
          bf16x8 af = *(const bf16x8*)(h1_prv + ((mt * 4 + kt) * 64 + lane) * 8);
          acc[mt][0] = MFMA16(af, b0_, acc[mt][0]);
          acc[mt][1] = MFMA16(af, b1_, acc[mt][1]);
          acc[mt][2] = MFMA16(af, b2_, acc[mt][2]);
          acc[mt][3] = MFMA16(af, b3_, acc[mt][3]);
        }
      }
      // cell 1 (for step t-1) + write h1_{t-1} frags
#pragma unroll
      for (int mt = 0; mt < 4; ++mt)
#pragma unroll
        for (int r = 0; r < 4; ++r) {
          float gi = frcp(1.0f + fexp2(fmaf(-1.4426950408889634f, acc[mt][0][r], sb1[0])));
          float gf = frcp(1.0f + fexp2(fmaf(-1.4426950408889634f, acc[mt][1][r], sb1[1])));
          float gg = 1.0f - 2.0f * frcp(1.0f + fexp2(fmaf(2.8853900817779268f, acc[mt][2][r], sb1[2])));
          float go = frcp(1.0f + fexp2(fmaf(-1.4426950408889634f, acc[mt][3][r], sb1[3])));
          float cn = gf * c1[mt * 4 + r] + gi * gg;
          c1[mt * 4 + r] = cn;
          float hn = go * tanh_f(cn);
          h1_cur[mt * 2048 + r * 8 + wr_off] = f2bf(hn);
        }
    }
    // ---- phase0(t): acc0 = x_t@W0x^T + h0_{t-1}@Whh0^T ----
    {
      f32x4 acc[4][4];
      {
        bf16x8 b0_ = *(const bf16x8*)(wp0);
        bf16x8 b1_ = *(const bf16x8*)(wp0 + 512);
        bf16x8 b2_ = *(const bf16x8*)(wp0 + 1024);
        bf16x8 b3_ = *(const bf16x8*)(wp0 + 1536);
#pragma unroll
        for (int mt = 0; mt < 4; ++mt) {
          acc[mt][0] = MFMA16(xf[mt], b0_, z4);
          acc[mt][1] = MFMA16(xf[mt], b1_, z4);
          acc[mt][2] = MFMA16(xf[mt], b2_, z4);
          acc[mt][3] = MFMA16(xf[mt], b3_, z4);
        }
      }
#pragma clang loop unroll_count(2)
      for (int kt = 0; kt < 4; ++kt) {
        const short* wb = wph + kt * 2048;
        bf16x8 b0_ = *(const bf16x8*)(wb);
        bf16x8 b1_ = *(const bf16x8*)(wb + 512);
        bf16x8 b2_ = *(const bf16x8*)(wb + 1024);
        bf16x8 b3_ = *(const bf16x8*)(wb + 1536);
#pragma unroll
        for (int mt = 0; mt < 4; ++mt) {
          bf16x8 af = *(const bf16x8*)(h0_prv + ((mt * 4 + kt) * 64 + lane) * 8);
          acc[mt][0] = MFMA16(af, b0_, acc[mt][0]);
          acc[mt][1] = MFMA16(af, b1_, acc[mt][1]);
          acc[mt][2] = MFMA16(af, b2_, acc[mt][2]);
          acc[mt][3] = MFMA16(af, b3_, acc[mt][3]);
        }
      }
      // cell 0 + write h0_t frags
#pragma unroll
      for (int mt = 0; mt < 4; ++mt)
#pragma unroll
        for (int r = 0; r < 4; ++r) {
          float gi = frcp(1.0f + fexp2(fmaf(-1.4426950408889634f, acc[mt][0][r], sb0[0])));
          float gf = frcp(1.0f + fexp2(fmaf(-1.4426950408889634f, acc[mt][1][r], sb0[1])));
          float gg = 1.0f - 2.0f * frcp(1.0f + fexp2(fmaf(2.8853900817779268f, acc[mt][2][r], sb0[2])));
          float go = frcp(1.0f + fexp2(fmaf(-1.4426950408889634f, acc[mt][3][r], sb0[3])));
          float cn = gf * c0[mt * 4 + r] + gi * gg;
          c0[mt * 4 + r] = cn;
          float hn = go * tanh_f(cn);
          h0_cur[mt * 2048 + r * 8 + wr_off] = f2bf(hn);
        }
    }
    __syncthreads();  // the ONE barrier: publishes h0_t and h1_{t-1}
    short* tp = h0_cur; h0_cur = h0_prv; h0_prv = tp;
    tp = h1_cur; h1_cur = h1_prv; h1_prv = tp;
  }

  // ================= drain: phase1(t=127) -> fp32 h1 straight to LDS =================
  {
    f32x4 acc[4][4];
    {
      const short* wb = wp1;
      bf16x8 b0_ = *(const bf16x8*)(wb);
      bf16x8 b1_ = *(const bf16x8*)(wb + 512);
      bf16x8 b2_ = *(const bf16x8*)(wb + 1024);
      bf16x8 b3_ = *(const bf16x8*)(wb + 1536);
#pragma unroll
      for (int mt = 0; mt < 4; ++mt) {
        bf16x8 af = *(const bf16x8*)(h0_prv + ((mt * 4 + 0) * 64 + lane) * 8);
        acc[mt][0] = MFMA16(af, b0_, z4);
        acc[mt][1] = MFMA16(af, b1_, z4);
        acc[mt][2] = MFMA16(af, b2_, z4);
        acc[mt][3] = MFMA16(af, b3_, z4);
      }
    }
#pragma unroll
    for (int kt = 1; kt < 4; ++kt) {
      const short* wb = wp1 + kt * 2048;
      bf16x8 b0_ = *(const bf16x8*)(wb);
      bf16x8 b1_ = *(const bf16x8*)(wb + 512);
      bf16x8 b2_ = *(const bf16x8*)(wb + 1024);
      bf16x8 b3_ = *(const bf16x8*)(wb + 1536);
#pragma unroll
      for (int mt = 0; mt < 4; ++mt) {
        bf16x8 af = *(const bf16x8*)(h0_prv + ((mt * 4 + kt) * 64 + lane) * 8);
        acc[mt][0] = MFMA16(af, b0_, acc[mt][0]);
        acc[mt][1] = MFMA16(af, b1_, acc[mt][1]);
        acc[mt][2] = MFMA16(af, b2_, acc[mt][2]);
        acc[mt][3] = MFMA16(af, b3_, acc[mt][3]);
      }
    }
#pragma unroll
    for (int kt = 0; kt < 4; ++kt) {
      const short* wb = wp1 + (kt + 4) * 2048;
      bf16x8 b0_ = *(const bf16x8*)(wb);
      bf16x8 b1_ = *(const bf16x8*)(wb + 512);
      bf16x8 b2_ = *(const bf16x8*)(wb + 1024);
      bf16x8 b3_ = *(const bf16x8*)(wb + 1536);
#pragma unroll
      for (int mt = 0; mt < 4; ++mt) {
        bf16x8 af = *(const bf16x8*)(h1_prv + ((mt * 4 + kt) * 64 + lane) * 8);
        acc[mt][0] = MFMA16(af, b0_, acc[mt][0]);
        acc[mt][1] = MFMA16(af, b1_, acc[mt][1]);
        acc[mt][2] = MFMA16(af, b2_, acc[mt][2]);
        acc[mt][3] = MFMA16(af, b3_, acc[mt][3]);
      }
    }
#pragma unroll
    for (int mt = 0; mt < 4; ++mt)
#pragma unroll
      for (int r = 0; r < 4; ++r) {
        float gi = frcp(1.0f + fexp2(fmaf(-1.4426950408889634f, acc[mt][0][r], sb1[0])));
        float gf = frcp(1.0f + fexp2(fmaf(-1.4426950408889634f, acc[mt][1][r], sb1[1])));
        float gg = 1.0f - 2.0f * frcp(1.0f + fexp2(fmaf(2.8853900817779268f, acc[mt][2][r], sb1[2])));
        float go = frcp(1.0f + fexp2(fmaf(-1.4426950408889634f, acc[mt][3][r], sb1[3])));
        float cn = gf * c1[mt * 4 + r] + gi * gg;
        float hn = go * tanh_f(cn);
        h1fp[(mt * 16 + quad * 4 + r) * HID + w * 16 + c] = hn;
      }
  }
  __syncthreads();  // h1fp complete before epilogue reads

  // ================= epilogue: logits = h1 @ Wout^T + bout, softmax over 12 =================
  {
    int row = tid >> 3, og = tid & 7;
    for (int oc = og; oc < OUT_N; oc += 8) {
      float s = bout[oc];
      const float* wo = Wout + oc * HID;
      const float* hr = h1fp + row * HID;
#pragma unroll 8
      for (int k = 0; k < HID; ++k) s += hr[k] * wo[k];
      lg[row * OUT_N + oc] = s;
    }
  }
  __syncthreads();
  if (tid < 64) {
    int row = tid;
    float m = lg[row * OUT_N];
#pragma unroll
    for (int oc = 1; oc < OUT_N; ++oc) m = fmaxf(m, lg[row * OUT_N + oc]);
    float e[OUT_N];
    float s = 0.f;
#pragma unroll
    for (int oc = 0; oc < OUT_N; ++oc) {
      e[oc] = __expf(lg[row * OUT_N + oc] - m);
      s += e[oc];
    }
    float inv = 1.0f / s;
    float* orow = out + (size_t)(rowbase + row) * OUT_N;
#pragma unroll
    for (int oc = 0; oc < OUT_N; ++oc) orow[oc] = e[oc] * inv;
  }
}

extern "C" void kernel_launch(void* const* d_in, const int* in_sizes, int n_in,
                              void* d_out, int out_size, void* d_ws, size_t ws_size,
                              hipStream_t stream) {
  const float* x    = (const float*)d_in[0];
  const float* W_in = (const float*)d_in[1];
  const float* b_in = (const float*)d_in[2];
  const float* Wih0 = (const float*)d_in[3];
  const float* Whh0 = (const float*)d_in[4];
  const float* bih0 = (const float*)d_in[5];
  const float* bhh0 = (const float*)d_in[6];
  const float* Wih1 = (const float*)d_in[7];
  const float* Whh1 = (const float*)d_in[8];
  const float* bih1 = (const float*)d_in[9];
  const float* bhh1 = (const float*)d_in[10];
  const float* Wout = (const float*)d_in[11];
  const float* bout = (const float*)d_in[12];
  float* out = (float*)d_out;

  // workspace layout (~420 KB): frag-packed bf16 weights + combined biases
  short* w0xf  = (short*)d_ws;            // 16384 shorts (32 KB)
  short* whh0f = w0xf + 16384;            // 65536 shorts (128 KB)
  short* w1f   = whh0f + 65536;           // 131072 shorts (256 KB)
  float* b0x   = (float*)(w1f + 131072);  // 512 f32
  float* b1    = b0x + 512;               // 512 f32

  prep_w0x<<<1, 512, 0, stream>>>(W_in, b_in, Wih0, bih0, bhh0, bih1, bhh1, w0xf, b0x, b1);
  prep_wrec<<<12, 512, 0, stream>>>(Whh0, Wih1, Whh1, whh0f, w1f);
  lstm_main<<<256, 512, 0, stream>>>(x, w0xf, whh0f, w1f, b0x, b1, Wout, bout, out);
}